// Round 15
// baseline (811.858 us; speedup 1.0000x reference)
//
#include <hip/hip_runtime.h>
#include <hip/hip_fp16.h>

#define T_TOK 2048
#define H_DIM 2048
#define E_NUM 64
#define TOPK  8
#define I_DIM 768

#define BK   32

#define GU_MT 2
#define GU_NT (I_DIM / 64)              // 12
#define GU_NWG (GU_MT * GU_NT * E_NUM)  // 1536, %8==0
#define DN_MT 2
#define DN_NT (H_DIM / 128)             // 16
#define DN_NWG (DN_MT * DN_NT * E_NUM)  // 2048, %8==0

using f16x8 = __attribute__((ext_vector_type(8))) _Float16;
using f16x4 = __attribute__((ext_vector_type(4))) _Float16;
using f16x2 = __attribute__((ext_vector_type(2))) _Float16;
using f32x4 = __attribute__((ext_vector_type(4))) float;

__device__ __forceinline__ f16x4 cvt4(float4 v) {
    f16x2 lo = __builtin_bit_cast(f16x2, __builtin_amdgcn_cvt_pkrtz(v.x, v.y));
    f16x2 hi = __builtin_bit_cast(f16x2, __builtin_amdgcn_cvt_pkrtz(v.z, v.w));
    f16x4 o;
    o[0] = lo[0]; o[1] = lo[1]; o[2] = hi[0]; o[3] = hi[1];
    return o;
}
__device__ __forceinline__ f16x8 cvt8(float4 a, float4 b) {
    f16x4 lo = cvt4(a), hi = cvt4(b);
    f16x8 r;
    r[0] = lo[0]; r[1] = lo[1]; r[2] = lo[2]; r[3] = lo[3];
    r[4] = hi[0]; r[5] = hi[1]; r[6] = hi[2]; r[7] = hi[3];
    return r;
}

// async global->LDS, 16B per lane. LDS dest = wave-uniform base + lane*16.
__device__ __forceinline__ void gload16(const void* g, void* l) {
    __builtin_amdgcn_global_load_lds(
        (const __attribute__((address_space(1))) unsigned int*)g,
        (__attribute__((address_space(3))) unsigned int*)l,
        16, 0, 0);
}

// ---------------- X fp32 -> fp16 ----------------
__global__ void convert_x_kernel(const float* __restrict__ x, _Float16* __restrict__ xh, int n) {
    int i = (blockIdx.x * blockDim.x + threadIdx.x) * 4;
    if (i < n) {
        float4 v = *reinterpret_cast<const float4*>(x + i);
        *reinterpret_cast<f16x4*>(xh + i) = cvt4(v);
    }
}

// ---------------- router + top-k (fp32, one wave per token) ----------------
__global__ __launch_bounds__(64) void router_topk_kernel(
        const float* __restrict__ x, const float* __restrict__ wr,
        int* __restrict__ topk_i, float* __restrict__ topk_w) {
    __shared__ float xs[H_DIM];
    int t = blockIdx.x;
    int lane = threadIdx.x;
    const float* xp = x + (size_t)t * H_DIM;
    for (int i = lane * 4; i < H_DIM; i += 64 * 4) {
        *reinterpret_cast<float4*>(xs + i) = *reinterpret_cast<const float4*>(xp + i);
    }
    __syncthreads();
    const float* wp = wr + (size_t)lane * H_DIM;
    float acc = 0.f;
    for (int h = 0; h < H_DIM; h += 4) {
        float4 w = *reinterpret_cast<const float4*>(wp + h);
        acc += xs[h] * w.x + xs[h + 1] * w.y + xs[h + 2] * w.z + xs[h + 3] * w.w;
    }
    float m = acc;
    #pragma unroll
    for (int d = 32; d; d >>= 1) m = fmaxf(m, __shfl_xor(m, d));
    float p = __expf(acc - m);
    float s = p;
    #pragma unroll
    for (int d = 32; d; d >>= 1) s += __shfl_xor(s, d);
    p /= s;
    float selv[TOPK]; int seli[TOPK];
    float cur = p;
    #pragma unroll
    for (int k = 0; k < TOPK; ++k) {
        float v = cur; int idx = lane;
        #pragma unroll
        for (int d = 32; d; d >>= 1) {
            float ov = __shfl_xor(v, d); int oi = __shfl_xor(idx, d);
            if (ov > v || (ov == v && oi < idx)) { v = ov; idx = oi; }
        }
        selv[k] = v; seli[k] = idx;
        if (lane == idx) cur = -1.f;
    }
    float sum = 0.f;
    #pragma unroll
    for (int k = 0; k < TOPK; ++k) sum += selv[k];
    if (lane == 0) {
        #pragma unroll
        for (int k = 0; k < TOPK; ++k) {
            topk_i[t * TOPK + k] = seli[k];
            topk_w[t * TOPK + k] = selv[k] / sum;
        }
    }
}

// ---------------- expert histogram / scan / scatter ----------------
__global__ void count_kernel(const int* __restrict__ topk_i, int* __restrict__ counts) {
    int i = blockIdx.x * blockDim.x + threadIdx.x;
    if (i < T_TOK * TOPK) atomicAdd(&counts[topk_i[i]], 1);
}

__global__ __launch_bounds__(64) void scan_kernel(const int* __restrict__ counts,
                                                  int* __restrict__ offsets,
                                                  int* __restrict__ cursor) {
    __shared__ int c[E_NUM];
    int e = threadIdx.x;
    c[e] = counts[e];
    __syncthreads();
    int off = 0;
    for (int j = 0; j < e; ++j) off += c[j];
    offsets[e] = off;
    cursor[e] = off;
}

__global__ void scatter_kernel(const int* __restrict__ topk_i, const float* __restrict__ topk_w,
                               int* __restrict__ cursor,
                               int* __restrict__ token_list, float* __restrict__ weight_list,
                               int* __restrict__ inv_slot) {
    int i = blockIdx.x * blockDim.x + threadIdx.x;
    if (i < T_TOK * TOPK) {
        int e = topk_i[i];
        int pos = atomicAdd(&cursor[e], 1);
        token_list[pos] = i >> 3;
        weight_list[pos] = topk_w[i];
        inv_slot[i] = pos;
    }
}

// ---------------- gate/up fused GEMM (r8/r13 structure) ----------------
// BM=128 x BN=64 (gate+up), BK=32. 4 waves 2x2. Single-buffered linear LDS,
// global_load_lds w=16, XOR-pre-swizzled source == XOR on ds_read.
__global__ __launch_bounds__(256) void gateup_kernel(
        const _Float16* __restrict__ xh, const float* __restrict__ wg,
        const float* __restrict__ wu, const int* __restrict__ offsets,
        const int* __restrict__ counts, const int* __restrict__ token_list,
        _Float16* __restrict__ hbuf) {
    int orig = blockIdx.x;
    int w = (orig & 7) * (GU_NWG / 8) + (orig >> 3);   // XCD-chunked (bijective)
    int mt = w % GU_MT;
    int nt = (w / GU_MT) % GU_NT;
    int e  = w / (GU_MT * GU_NT);
    int n_e = counts[e];
    int off_e = offsets[e];
    int n_base = nt * 64;
    const float* wg_e = wg + (size_t)e * I_DIM * H_DIM;
    const float* wu_e = wu + (size_t)e * I_DIM * H_DIM;

    __shared__ __align__(16) _Float16 As[128 * 32];   // 8 KB
    __shared__ __align__(16) float    Bgs[64 * 32];   // 8 KB
    __shared__ __align__(16) float    Bus[64 * 32];   // 8 KB
    __shared__ int toks[128];

    int tid = threadIdx.x;
    int ar = tid >> 2, aslot = tid & 3;
    int acf = aslot ^ (ar & 3);
    int brr = tid >> 3, bslot = tid & 7;
    int bcf = bslot ^ (brr & 7);
    const float* bg0 = wg_e + (size_t)(n_base + brr) * H_DIM + bcf * 4;
    const float* bg1 = wg_e + (size_t)(n_base + 32 + brr) * H_DIM + bcf * 4;
    const float* bu0 = wu_e + (size_t)(n_base + brr) * H_DIM + bcf * 4;
    const float* bu1 = wu_e + (size_t)(n_base + 32 + brr) * H_DIM + bcf * 4;

    int wave = tid >> 6, lane = tid & 63;
    int wm = wave >> 1, wn = wave & 1;
    int aoff[4];
    #pragma unroll
    for (int fm = 0; fm < 4; ++fm) {
        int row = wm * 64 + fm * 16 + (lane & 15);
        aoff[fm] = row * 32 + ((lane >> 4) ^ (lane & 3)) * 8;
    }
    int boff0[2], boff1[2];
    #pragma unroll
    for (int fn = 0; fn < 2; ++fn) {
        int row = wn * 32 + fn * 16 + (lane & 15);
        int c0 = (lane >> 4) * 2;
        boff0[fn] = row * 32 + (c0 ^ (lane & 7)) * 4;
        boff1[fn] = row * 32 + ((c0 + 1) ^ (lane & 7)) * 4;
    }

    for (int m_base = mt * 128; m_base < n_e; m_base += GU_MT * 128) {
        if (tid < 128) toks[tid] = token_list[off_e + min(m_base + tid, n_e - 1)];
        __syncthreads();
        const _Float16* asrc0 = xh + (size_t)toks[ar] * H_DIM + acf * 8;
        const _Float16* asrc1 = xh + (size_t)toks[64 + ar] * H_DIM + acf * 8;

        f32x4 accg[4][2], accu[4][2];
        #pragma unroll
        for (int i = 0; i < 4; ++i)
            #pragma unroll
            for (int j = 0; j < 2; ++j) { accg[i][j] = (f32x4)0.f; accu[i][j] = (f32x4)0.f; }

        for (int t = 0; t < H_DIM / BK; ++t) {
            int k0 = t * BK;
            gload16(asrc0 + k0, As + tid * 8);
            gload16(asrc1 + k0, As + 2048 + tid * 8);
            gload16(bg0 + k0, Bgs + tid * 4);
            gload16(bg1 + k0, Bgs + 1024 + tid * 4);
            gload16(bu0 + k0, Bus + tid * 4);
            gload16(bu1 + k0, Bus + 1024 + tid * 4);
            __syncthreads();
            f16x8 a[4];
            #pragma unroll
            for (int fm = 0; fm < 4; ++fm) a[fm] = *reinterpret_cast<const f16x8*>(&As[aoff[fm]]);
            #pragma unroll
            for (int fn = 0; fn < 2; ++fn) {
                float4 g0 = *reinterpret_cast<const float4*>(&Bgs[boff0[fn]]);
                float4 g1 = *reinterpret_cast<const float4*>(&Bgs[boff1[fn]]);
                float4 u0 = *reinterpret_cast<const float4*>(&Bus[boff0[fn]]);
                float4 u1 = *reinterpret_cast<const float4*>(&Bus[boff1[fn]]);
                f16x8 bgf = cvt8(g0, g1);
                f16x8 buf = cvt8(u0, u1);
                #pragma unroll
                for (int fm = 0; fm < 4; ++fm) {
                    accg[fm][fn] = __builtin_amdgcn_mfma_f32_16x16x32_f16(a[fm], bgf, accg[fm][fn], 0, 0, 0);
                    accu[fm][fn] = __builtin_amdgcn_mfma_f32_16x16x32_f16(a[fm], buf, accu[fm][fn], 0, 0, 0);
                }
            }
            __syncthreads();
        }

        // epilogue: h = silu(g)*u
        #pragma unroll
        for (int fm = 0; fm < 4; ++fm) {
            #pragma unroll
            for (int reg = 0; reg < 4; ++reg) {
                int row = wm * 64 + fm * 16 + (lane >> 4) * 4 + reg;
                int m = m_base + row;
                if (m < n_e) {
                    #pragma unroll
                    for (int fn = 0; fn < 2; ++fn) {
                        int col = wn * 32 + fn * 16 + (lane & 15);
                        float g = accg[fm][fn][reg];
                        float u = accu[fm][fn][reg];
                        float hv = g * u / (1.f + __expf(-g));
                        hbuf[(size_t)(off_e + m) * I_DIM + n_base + col] = (_Float16)hv;
                    }
                }
            }
        }
        __syncthreads();
    }
}

// ---------------- down GEMM: r13 structure, NO atomics ----------------
// BM=128 x BN=128, BK=32. 4 waves 2x2. Weighted fp16 stores into per-slot ybuf.
__global__ __launch_bounds__(256) void down_kernel(
        const _Float16* __restrict__ hbuf, const float* __restrict__ wd,
        const int* __restrict__ offsets, const int* __restrict__ counts,
        const int* __restrict__ token_list, const float* __restrict__ weight_list,
        _Float16* __restrict__ ybuf) {
    int orig = blockIdx.x;
    int w = (orig & 7) * (DN_NWG / 8) + (orig >> 3);
    int mt = w % DN_MT;
    int nt = (w / DN_MT) % DN_NT;
    int e  = w / (DN_MT * DN_NT);
    int n_e = counts[e];
    int off_e = offsets[e];
    int n_base = nt * 128;
    const float* wd_e = wd + (size_t)e * H_DIM * I_DIM;

    __shared__ __align__(16) _Float16 As[128 * 32];   // 8 KB
    __shared__ __align__(16) float    Bs[128 * 32];   // 16 KB

    int tid = threadIdx.x;
    int ar = tid >> 2, aslot = tid & 3;
    int acf = aslot ^ (ar & 3);
    int brr = tid >> 3, bslot = tid & 7;
    int bcf = bslot ^ (brr & 7);
    const float* bs0 = wd_e + (size_t)(n_base + brr) * I_DIM + bcf * 4;
    const float* bs1 = bs0 + (size_t)32 * I_DIM;
    const float* bs2 = bs0 + (size_t)64 * I_DIM;
    const float* bs3 = bs0 + (size_t)96 * I_DIM;

    int wave = tid >> 6, lane = tid & 63;
    int wm = wave >> 1, wn = wave & 1;
    int aoff[4];
    #pragma unroll
    for (int fm = 0; fm < 4; ++fm) {
        int row = wm * 64 + fm * 16 + (lane & 15);
        aoff[fm] = row * 32 + ((lane >> 4) ^ (lane & 3)) * 8;
    }
    int boff0[4], boff1[4];
    #pragma unroll
    for (int fn = 0; fn < 4; ++fn) {
        int row = wn * 64 + fn * 16 + (lane & 15);
        int c0 = (lane >> 4) * 2;
        boff0[fn] = row * 32 + (c0 ^ (lane & 7)) * 4;
        boff1[fn] = row * 32 + ((c0 + 1) ^ (lane & 7)) * 4;
    }

    for (int m_base = mt * 128; m_base < n_e; m_base += DN_MT * 128) {
        int am0 = min(m_base + ar, n_e - 1);
        int am1 = min(m_base + 64 + ar, n_e - 1);
        const _Float16* asrc0 = hbuf + (size_t)(off_e + am0) * I_DIM + acf * 8;
        const _Float16* asrc1 = hbuf + (size_t)(off_e + am1) * I_DIM + acf * 8;

        f32x4 acc[4][4];
        #pragma unroll
        for (int i = 0; i < 4; ++i)
            #pragma unroll
            for (int j = 0; j < 4; ++j) acc[i][j] = (f32x4)0.f;

        for (int t = 0; t < I_DIM / BK; ++t) {
            int k0 = t * BK;
            gload16(asrc0 + k0, As + tid * 8);
            gload16(asrc1 + k0, As + 2048 + tid * 8);
            gload16(bs0 + k0, Bs + tid * 4);
            gload16(bs1 + k0, Bs + 1024 + tid * 4);
            gload16(bs2 + k0, Bs + 2048 + tid * 4);
            gload16(bs3 + k0, Bs + 3072 + tid * 4);
            __syncthreads();
            f16x8 a[4];
            #pragma unroll
            for (int fm = 0; fm < 4; ++fm) a[fm] = *reinterpret_cast<const f16x8*>(&As[aoff[fm]]);
            #pragma unroll
            for (int fn = 0; fn < 4; ++fn) {
                float4 v0 = *reinterpret_cast<const float4*>(&Bs[boff0[fn]]);
                float4 v1 = *reinterpret_cast<const float4*>(&Bs[boff1[fn]]);
                f16x8 bb = cvt8(v0, v1);
                #pragma unroll
                for (int fm = 0; fm < 4; ++fm)
                    acc[fm][fn] = __builtin_amdgcn_mfma_f32_16x16x32_f16(a[fm], bb, acc[fm][fn], 0, 0, 0);
            }
            __syncthreads();
        }

        // epilogue: plain weighted fp16 stores into ybuf
        #pragma unroll
        for (int fm = 0; fm < 4; ++fm) {
            #pragma unroll
            for (int reg = 0; reg < 4; ++reg) {
                int m = m_base + wm * 64 + fm * 16 + (lane >> 4) * 4 + reg;
                if (m < n_e) {
                    int slot = off_e + m;
                    float wt = weight_list[slot];
                    _Float16* yrow = ybuf + (size_t)slot * H_DIM + n_base;
                    #pragma unroll
                    for (int fn = 0; fn < 4; ++fn) {
                        int col = wn * 64 + fn * 16 + (lane & 15);
                        yrow[col] = (_Float16)(wt * acc[fm][fn][reg]);
                    }
                }
            }
        }
        __syncthreads();
    }
}

// ---------------- reduce: out[t] = sum_k ybuf[slot(t,k)] ----------------
__global__ __launch_bounds__(256) void reduce_kernel(
        const _Float16* __restrict__ ybuf, const int* __restrict__ inv_slot,
        float* __restrict__ out) {
    int t = blockIdx.x;
    int c = threadIdx.x * 8;
    int s[TOPK];
    #pragma unroll
    for (int k = 0; k < TOPK; ++k) s[k] = inv_slot[t * TOPK + k];
    float sum[8];
    #pragma unroll
    for (int j = 0; j < 8; ++j) sum[j] = 0.f;
    #pragma unroll
    for (int k = 0; k < TOPK; ++k) {
        f16x8 v = *reinterpret_cast<const f16x8*>(ybuf + (size_t)s[k] * H_DIM + c);
        #pragma unroll
        for (int j = 0; j < 8; ++j) sum[j] += (float)v[j];
    }
    float* orow = out + (size_t)t * H_DIM + c;
    float4 o0, o1;
    o0.x = sum[0]; o0.y = sum[1]; o0.z = sum[2]; o0.w = sum[3];
    o1.x = sum[4]; o1.y = sum[5]; o1.z = sum[6]; o1.w = sum[7];
    *reinterpret_cast<float4*>(orow) = o0;
    *reinterpret_cast<float4*>(orow + 4) = o1;
}

extern "C" void kernel_launch(void* const* d_in, const int* in_sizes, int n_in,
                              void* d_out, int out_size, void* d_ws, size_t ws_size,
                              hipStream_t stream) {
    const float* x  = (const float*)d_in[0];
    const float* wr = (const float*)d_in[1];
    const float* wg = (const float*)d_in[2];
    const float* wu = (const float*)d_in[3];
    const float* wd = (const float*)d_in[4];
    float* out = (float*)d_out;

    char* p = (char*)d_ws;
    auto carve = [&](size_t bytes) { char* q = p; p += (bytes + 255) & ~255ULL; return q; };
    _Float16* xh     = (_Float16*)carve((size_t)T_TOK * H_DIM * 2);             // 8 MB
    _Float16* hbuf   = (_Float16*)carve((size_t)T_TOK * TOPK * I_DIM * 2);      // 24 MB
    _Float16* ybuf   = (_Float16*)carve((size_t)T_TOK * TOPK * H_DIM * 2);      // 64 MB
    int*   topk_i    = (int*)  carve(T_TOK * TOPK * 4);
    float* topk_w    = (float*)carve(T_TOK * TOPK * 4);
    int*   tlist     = (int*)  carve(T_TOK * TOPK * 4);
    float* wlist     = (float*)carve(T_TOK * TOPK * 4);
    int*   inv_slot  = (int*)  carve(T_TOK * TOPK * 4);
    int*   counts    = (int*)  carve(E_NUM * 4);
    int*   offsets   = (int*)  carve(E_NUM * 4);
    int*   cursor    = (int*)  carve(E_NUM * 4);

    (void)hipMemsetAsync(counts, 0, E_NUM * 4, stream);

    convert_x_kernel<<<(T_TOK * H_DIM) / (256 * 4), 256, 0, stream>>>(x, xh, T_TOK * H_DIM);
    router_topk_kernel<<<T_TOK, 64, 0, stream>>>(x, wr, topk_i, topk_w);
    count_kernel<<<(T_TOK * TOPK) / 256, 256, 0, stream>>>(topk_i, counts);
    scan_kernel<<<1, 64, 0, stream>>>(counts, offsets, cursor);
    scatter_kernel<<<(T_TOK * TOPK) / 256, 256, 0, stream>>>(topk_i, topk_w, cursor, tlist, wlist, inv_slot);
    gateup_kernel<<<GU_NWG, 256, 0, stream>>>(xh, wg, wu, offsets, counts, tlist, hbuf);
    down_kernel<<<DN_NWG, 256, 0, stream>>>(hbuf, wd, offsets, counts, tlist, wlist, ybuf);
    reduce_kernel<<<T_TOK, 256, 0, stream>>>(ybuf, inv_slot, out);
}

// Round 16
// 659.104 us; speedup vs baseline: 1.2318x; 1.2318x over previous
//
#include <hip/hip_runtime.h>
#include <hip/hip_fp16.h>

#define T_TOK 2048
#define H_DIM 2048
#define E_NUM 64
#define TOPK  8
#define I_DIM 768

#define BK   32

#define GU_MT 3
#define GU_NT (I_DIM / 64)              // 12
#define GU_NWG (GU_MT * GU_NT * E_NUM)  // 2304, %8==0
#define DN_MT 3
#define DN_NT (H_DIM / 128)             // 16
#define DN_NWG (DN_MT * DN_NT * E_NUM)  // 3072, %8==0

using f16x8 = __attribute__((ext_vector_type(8))) _Float16;
using f16x4 = __attribute__((ext_vector_type(4))) _Float16;
using f16x2 = __attribute__((ext_vector_type(2))) _Float16;
using f32x4 = __attribute__((ext_vector_type(4))) float;

__device__ __forceinline__ f16x4 cvt4(float4 v) {
    f16x2 lo = __builtin_bit_cast(f16x2, __builtin_amdgcn_cvt_pkrtz(v.x, v.y));
    f16x2 hi = __builtin_bit_cast(f16x2, __builtin_amdgcn_cvt_pkrtz(v.z, v.w));
    f16x4 o;
    o[0] = lo[0]; o[1] = lo[1]; o[2] = hi[0]; o[3] = hi[1];
    return o;
}
__device__ __forceinline__ f16x8 cvt8(float4 a, float4 b) {
    f16x4 lo = cvt4(a), hi = cvt4(b);
    f16x8 r;
    r[0] = lo[0]; r[1] = lo[1]; r[2] = lo[2]; r[3] = lo[3];
    r[4] = hi[0]; r[5] = hi[1]; r[6] = hi[2]; r[7] = hi[3];
    return r;
}

// async global->LDS, 16B per lane. LDS dest = wave-uniform base + lane*16.
__device__ __forceinline__ void gload16(const void* g, void* l) {
    __builtin_amdgcn_global_load_lds(
        (const __attribute__((address_space(1))) unsigned int*)g,
        (__attribute__((address_space(3))) unsigned int*)l,
        16, 0, 0);
}

// ---------------- X fp32 -> fp16 ----------------
__global__ void convert_x_kernel(const float* __restrict__ x, _Float16* __restrict__ xh, int n) {
    int i = (blockIdx.x * blockDim.x + threadIdx.x) * 4;
    if (i < n) {
        float4 v = *reinterpret_cast<const float4*>(x + i);
        *reinterpret_cast<f16x4*>(xh + i) = cvt4(v);
    }
}

// ---------------- router + top-k (fp32, one wave per token) ----------------
__global__ __launch_bounds__(64) void router_topk_kernel(
        const float* __restrict__ x, const float* __restrict__ wr,
        int* __restrict__ topk_i, float* __restrict__ topk_w) {
    __shared__ float xs[H_DIM];
    int t = blockIdx.x;
    int lane = threadIdx.x;
    const float* xp = x + (size_t)t * H_DIM;
    for (int i = lane * 4; i < H_DIM; i += 64 * 4) {
        *reinterpret_cast<float4*>(xs + i) = *reinterpret_cast<const float4*>(xp + i);
    }
    __syncthreads();
    const float* wp = wr + (size_t)lane * H_DIM;
    float acc = 0.f;
    for (int h = 0; h < H_DIM; h += 4) {
        float4 w = *reinterpret_cast<const float4*>(wp + h);
        acc += xs[h] * w.x + xs[h + 1] * w.y + xs[h + 2] * w.z + xs[h + 3] * w.w;
    }
    float m = acc;
    #pragma unroll
    for (int d = 32; d; d >>= 1) m = fmaxf(m, __shfl_xor(m, d));
    float p = __expf(acc - m);
    float s = p;
    #pragma unroll
    for (int d = 32; d; d >>= 1) s += __shfl_xor(s, d);
    p /= s;
    float selv[TOPK]; int seli[TOPK];
    float cur = p;
    #pragma unroll
    for (int k = 0; k < TOPK; ++k) {
        float v = cur; int idx = lane;
        #pragma unroll
        for (int d = 32; d; d >>= 1) {
            float ov = __shfl_xor(v, d); int oi = __shfl_xor(idx, d);
            if (ov > v || (ov == v && oi < idx)) { v = ov; idx = oi; }
        }
        selv[k] = v; seli[k] = idx;
        if (lane == idx) cur = -1.f;
    }
    float sum = 0.f;
    #pragma unroll
    for (int k = 0; k < TOPK; ++k) sum += selv[k];
    if (lane == 0) {
        #pragma unroll
        for (int k = 0; k < TOPK; ++k) {
            topk_i[t * TOPK + k] = seli[k];
            topk_w[t * TOPK + k] = selv[k] / sum;
        }
    }
}

// ---------------- expert histogram / scan / scatter ----------------
__global__ void count_kernel(const int* __restrict__ topk_i, int* __restrict__ counts) {
    int i = blockIdx.x * blockDim.x + threadIdx.x;
    if (i < T_TOK * TOPK) atomicAdd(&counts[topk_i[i]], 1);
}

__global__ __launch_bounds__(64) void scan_kernel(const int* __restrict__ counts,
                                                  int* __restrict__ offsets,
                                                  int* __restrict__ cursor) {
    __shared__ int c[E_NUM];
    int e = threadIdx.x;
    c[e] = counts[e];
    __syncthreads();
    int off = 0;
    for (int j = 0; j < e; ++j) off += c[j];
    offsets[e] = off;
    cursor[e] = off;
}

__global__ void scatter_kernel(const int* __restrict__ topk_i, const float* __restrict__ topk_w,
                               int* __restrict__ cursor,
                               int* __restrict__ token_list, float* __restrict__ weight_list,
                               int* __restrict__ inv_slot) {
    int i = blockIdx.x * blockDim.x + threadIdx.x;
    if (i < T_TOK * TOPK) {
        int e = topk_i[i];
        int pos = atomicAdd(&cursor[e], 1);
        token_list[pos] = i >> 3;
        weight_list[pos] = topk_w[i];
        inv_slot[i] = pos;
    }
}

// ---------------- gate/up fused GEMM (r8 structure) ----------------
// BM=128 x BN=64 (gate+up), BK=32. 4 waves 2x2. Single-buffered linear LDS,
// global_load_lds w=16, XOR-pre-swizzled source == XOR on ds_read.
// GU_MT=3: mt=2 blocks are near-empty ballast — measured load-bearing
// (dispatch pacing / twin L2-timing; removing them cost +33%, r15).
__global__ __launch_bounds__(256) void gateup_kernel(
        const _Float16* __restrict__ xh, const float* __restrict__ wg,
        const float* __restrict__ wu, const int* __restrict__ offsets,
        const int* __restrict__ counts, const int* __restrict__ token_list,
        _Float16* __restrict__ hbuf) {
    int orig = blockIdx.x;
    int w = (orig & 7) * (GU_NWG / 8) + (orig >> 3);   // XCD-chunked (bijective)
    int mt = w % GU_MT;
    int nt = (w / GU_MT) % GU_NT;
    int e  = w / (GU_MT * GU_NT);
    int n_e = counts[e];
    int off_e = offsets[e];
    int n_base = nt * 64;
    const float* wg_e = wg + (size_t)e * I_DIM * H_DIM;
    const float* wu_e = wu + (size_t)e * I_DIM * H_DIM;

    __shared__ __align__(16) _Float16 As[128 * 32];   // 8 KB
    __shared__ __align__(16) float    Bgs[64 * 32];   // 8 KB
    __shared__ __align__(16) float    Bus[64 * 32];   // 8 KB
    __shared__ int toks[128];

    int tid = threadIdx.x;
    int ar = tid >> 2, aslot = tid & 3;
    int acf = aslot ^ (ar & 3);
    int brr = tid >> 3, bslot = tid & 7;
    int bcf = bslot ^ (brr & 7);
    const float* bg0 = wg_e + (size_t)(n_base + brr) * H_DIM + bcf * 4;
    const float* bg1 = wg_e + (size_t)(n_base + 32 + brr) * H_DIM + bcf * 4;
    const float* bu0 = wu_e + (size_t)(n_base + brr) * H_DIM + bcf * 4;
    const float* bu1 = wu_e + (size_t)(n_base + 32 + brr) * H_DIM + bcf * 4;

    int wave = tid >> 6, lane = tid & 63;
    int wm = wave >> 1, wn = wave & 1;
    int aoff[4];
    #pragma unroll
    for (int fm = 0; fm < 4; ++fm) {
        int row = wm * 64 + fm * 16 + (lane & 15);
        aoff[fm] = row * 32 + ((lane >> 4) ^ (lane & 3)) * 8;
    }
    int boff0[2], boff1[2];
    #pragma unroll
    for (int fn = 0; fn < 2; ++fn) {
        int row = wn * 32 + fn * 16 + (lane & 15);
        int c0 = (lane >> 4) * 2;
        boff0[fn] = row * 32 + (c0 ^ (lane & 7)) * 4;
        boff1[fn] = row * 32 + ((c0 + 1) ^ (lane & 7)) * 4;
    }

    for (int m_base = mt * 128; m_base < n_e; m_base += GU_MT * 128) {
        if (tid < 128) toks[tid] = token_list[off_e + min(m_base + tid, n_e - 1)];
        __syncthreads();
        const _Float16* asrc0 = xh + (size_t)toks[ar] * H_DIM + acf * 8;
        const _Float16* asrc1 = xh + (size_t)toks[64 + ar] * H_DIM + acf * 8;

        f32x4 accg[4][2], accu[4][2];
        #pragma unroll
        for (int i = 0; i < 4; ++i)
            #pragma unroll
            for (int j = 0; j < 2; ++j) { accg[i][j] = (f32x4)0.f; accu[i][j] = (f32x4)0.f; }

        for (int t = 0; t < H_DIM / BK; ++t) {
            int k0 = t * BK;
            gload16(asrc0 + k0, As + tid * 8);
            gload16(asrc1 + k0, As + 2048 + tid * 8);
            gload16(bg0 + k0, Bgs + tid * 4);
            gload16(bg1 + k0, Bgs + 1024 + tid * 4);
            gload16(bu0 + k0, Bus + tid * 4);
            gload16(bu1 + k0, Bus + 1024 + tid * 4);
            __syncthreads();
            f16x8 a[4];
            #pragma unroll
            for (int fm = 0; fm < 4; ++fm) a[fm] = *reinterpret_cast<const f16x8*>(&As[aoff[fm]]);
            #pragma unroll
            for (int fn = 0; fn < 2; ++fn) {
                float4 g0 = *reinterpret_cast<const float4*>(&Bgs[boff0[fn]]);
                float4 g1 = *reinterpret_cast<const float4*>(&Bgs[boff1[fn]]);
                float4 u0 = *reinterpret_cast<const float4*>(&Bus[boff0[fn]]);
                float4 u1 = *reinterpret_cast<const float4*>(&Bus[boff1[fn]]);
                f16x8 bgf = cvt8(g0, g1);
                f16x8 buf = cvt8(u0, u1);
                #pragma unroll
                for (int fm = 0; fm < 4; ++fm) {
                    accg[fm][fn] = __builtin_amdgcn_mfma_f32_16x16x32_f16(a[fm], bgf, accg[fm][fn], 0, 0, 0);
                    accu[fm][fn] = __builtin_amdgcn_mfma_f32_16x16x32_f16(a[fm], buf, accu[fm][fn], 0, 0, 0);
                }
            }
            __syncthreads();
        }

        // epilogue: h = silu(g)*u
        #pragma unroll
        for (int fm = 0; fm < 4; ++fm) {
            #pragma unroll
            for (int reg = 0; reg < 4; ++reg) {
                int row = wm * 64 + fm * 16 + (lane >> 4) * 4 + reg;
                int m = m_base + row;
                if (m < n_e) {
                    #pragma unroll
                    for (int fn = 0; fn < 2; ++fn) {
                        int col = wn * 32 + fn * 16 + (lane & 15);
                        float g = accg[fm][fn][reg];
                        float u = accu[fm][fn][reg];
                        float hv = g * u / (1.f + __expf(-g));
                        hbuf[(size_t)(off_e + m) * I_DIM + n_base + col] = (_Float16)hv;
                    }
                }
            }
        }
        __syncthreads();
    }
}

// ---------------- down GEMM: r8 structure, NO atomics ----------------
// BM=128 x BN=128, BK=32. 4 waves 2x2. Weighted fp16 stores into per-slot ybuf.
__global__ __launch_bounds__(256) void down_kernel(
        const _Float16* __restrict__ hbuf, const float* __restrict__ wd,
        const int* __restrict__ offsets, const int* __restrict__ counts,
        const int* __restrict__ token_list, const float* __restrict__ weight_list,
        _Float16* __restrict__ ybuf) {
    int orig = blockIdx.x;
    int w = (orig & 7) * (DN_NWG / 8) + (orig >> 3);
    int mt = w % DN_MT;
    int nt = (w / DN_MT) % DN_NT;
    int e  = w / (DN_MT * DN_NT);
    int n_e = counts[e];
    int off_e = offsets[e];
    int n_base = nt * 128;
    const float* wd_e = wd + (size_t)e * H_DIM * I_DIM;

    __shared__ __align__(16) _Float16 As[128 * 32];   // 8 KB
    __shared__ __align__(16) float    Bs[128 * 32];   // 16 KB

    int tid = threadIdx.x;
    int ar = tid >> 2, aslot = tid & 3;
    int acf = aslot ^ (ar & 3);
    int brr = tid >> 3, bslot = tid & 7;
    int bcf = bslot ^ (brr & 7);
    const float* bs0 = wd_e + (size_t)(n_base + brr) * I_DIM + bcf * 4;
    const float* bs1 = bs0 + (size_t)32 * I_DIM;
    const float* bs2 = bs0 + (size_t)64 * I_DIM;
    const float* bs3 = bs0 + (size_t)96 * I_DIM;

    int wave = tid >> 6, lane = tid & 63;
    int wm = wave >> 1, wn = wave & 1;
    int aoff[4];
    #pragma unroll
    for (int fm = 0; fm < 4; ++fm) {
        int row = wm * 64 + fm * 16 + (lane & 15);
        aoff[fm] = row * 32 + ((lane >> 4) ^ (lane & 3)) * 8;
    }
    int boff0[4], boff1[4];
    #pragma unroll
    for (int fn = 0; fn < 4; ++fn) {
        int row = wn * 64 + fn * 16 + (lane & 15);
        int c0 = (lane >> 4) * 2;
        boff0[fn] = row * 32 + (c0 ^ (lane & 7)) * 4;
        boff1[fn] = row * 32 + ((c0 + 1) ^ (lane & 7)) * 4;
    }

    for (int m_base = mt * 128; m_base < n_e; m_base += DN_MT * 128) {
        int am0 = min(m_base + ar, n_e - 1);
        int am1 = min(m_base + 64 + ar, n_e - 1);
        const _Float16* asrc0 = hbuf + (size_t)(off_e + am0) * I_DIM + acf * 8;
        const _Float16* asrc1 = hbuf + (size_t)(off_e + am1) * I_DIM + acf * 8;

        f32x4 acc[4][4];
        #pragma unroll
        for (int i = 0; i < 4; ++i)
            #pragma unroll
            for (int j = 0; j < 4; ++j) acc[i][j] = (f32x4)0.f;

        for (int t = 0; t < I_DIM / BK; ++t) {
            int k0 = t * BK;
            gload16(asrc0 + k0, As + tid * 8);
            gload16(asrc1 + k0, As + 2048 + tid * 8);
            gload16(bs0 + k0, Bs + tid * 4);
            gload16(bs1 + k0, Bs + 1024 + tid * 4);
            gload16(bs2 + k0, Bs + 2048 + tid * 4);
            gload16(bs3 + k0, Bs + 3072 + tid * 4);
            __syncthreads();
            f16x8 a[4];
            #pragma unroll
            for (int fm = 0; fm < 4; ++fm) a[fm] = *reinterpret_cast<const f16x8*>(&As[aoff[fm]]);
            #pragma unroll
            for (int fn = 0; fn < 4; ++fn) {
                float4 v0 = *reinterpret_cast<const float4*>(&Bs[boff0[fn]]);
                float4 v1 = *reinterpret_cast<const float4*>(&Bs[boff1[fn]]);
                f16x8 bb = cvt8(v0, v1);
                #pragma unroll
                for (int fm = 0; fm < 4; ++fm)
                    acc[fm][fn] = __builtin_amdgcn_mfma_f32_16x16x32_f16(a[fm], bb, acc[fm][fn], 0, 0, 0);
            }
            __syncthreads();
        }

        // epilogue: plain weighted fp16 stores into ybuf
        #pragma unroll
        for (int fm = 0; fm < 4; ++fm) {
            #pragma unroll
            for (int reg = 0; reg < 4; ++reg) {
                int m = m_base + wm * 64 + fm * 16 + (lane >> 4) * 4 + reg;
                if (m < n_e) {
                    int slot = off_e + m;
                    float wt = weight_list[slot];
                    _Float16* yrow = ybuf + (size_t)slot * H_DIM + n_base;
                    #pragma unroll
                    for (int fn = 0; fn < 4; ++fn) {
                        int col = wn * 64 + fn * 16 + (lane & 15);
                        yrow[col] = (_Float16)(wt * acc[fm][fn][reg]);
                    }
                }
            }
        }
        __syncthreads();
    }
}

// ---------------- reduce: out[t] = sum_k ybuf[slot(t,k)] ----------------
__global__ __launch_bounds__(256) void reduce_kernel(
        const _Float16* __restrict__ ybuf, const int* __restrict__ inv_slot,
        float* __restrict__ out) {
    int t = blockIdx.x;
    int c = threadIdx.x * 8;
    int s[TOPK];
    #pragma unroll
    for (int k = 0; k < TOPK; ++k) s[k] = inv_slot[t * TOPK + k];
    float sum[8];
    #pragma unroll
    for (int j = 0; j < 8; ++j) sum[j] = 0.f;
    #pragma unroll
    for (int k = 0; k < TOPK; ++k) {
        f16x8 v = *reinterpret_cast<const f16x8*>(ybuf + (size_t)s[k] * H_DIM + c);
        #pragma unroll
        for (int j = 0; j < 8; ++j) sum[j] += (float)v[j];
    }
    float* orow = out + (size_t)t * H_DIM + c;
    float4 o0, o1;
    o0.x = sum[0]; o0.y = sum[1]; o0.z = sum[2]; o0.w = sum[3];
    o1.x = sum[4]; o1.y = sum[5]; o1.z = sum[6]; o1.w = sum[7];
    *reinterpret_cast<float4*>(orow) = o0;
    *reinterpret_cast<float4*>(orow + 4) = o1;
}

extern "C" void kernel_launch(void* const* d_in, const int* in_sizes, int n_in,
                              void* d_out, int out_size, void* d_ws, size_t ws_size,
                              hipStream_t stream) {
    const float* x  = (const float*)d_in[0];
    const float* wr = (const float*)d_in[1];
    const float* wg = (const float*)d_in[2];
    const float* wu = (const float*)d_in[3];
    const float* wd = (const float*)d_in[4];
    float* out = (float*)d_out;

    char* p = (char*)d_ws;
    auto carve = [&](size_t bytes) { char* q = p; p += (bytes + 255) & ~255ULL; return q; };
    _Float16* xh     = (_Float16*)carve((size_t)T_TOK * H_DIM * 2);             // 8 MB
    _Float16* hbuf   = (_Float16*)carve((size_t)T_TOK * TOPK * I_DIM * 2);      // 24 MB
    _Float16* ybuf   = (_Float16*)carve((size_t)T_TOK * TOPK * H_DIM * 2);      // 64 MB
    int*   topk_i    = (int*)  carve(T_TOK * TOPK * 4);
    float* topk_w    = (float*)carve(T_TOK * TOPK * 4);
    int*   tlist     = (int*)  carve(T_TOK * TOPK * 4);
    float* wlist     = (float*)carve(T_TOK * TOPK * 4);
    int*   inv_slot  = (int*)  carve(T_TOK * TOPK * 4);
    int*   counts    = (int*)  carve(E_NUM * 4);
    int*   offsets   = (int*)  carve(E_NUM * 4);
    int*   cursor    = (int*)  carve(E_NUM * 4);

    (void)hipMemsetAsync(counts, 0, E_NUM * 4, stream);

    convert_x_kernel<<<(T_TOK * H_DIM) / (256 * 4), 256, 0, stream>>>(x, xh, T_TOK * H_DIM);
    router_topk_kernel<<<T_TOK, 64, 0, stream>>>(x, wr, topk_i, topk_w);
    count_kernel<<<(T_TOK * TOPK) / 256, 256, 0, stream>>>(topk_i, counts);
    scan_kernel<<<1, 64, 0, stream>>>(counts, offsets, cursor);
    scatter_kernel<<<(T_TOK * TOPK) / 256, 256, 0, stream>>>(topk_i, topk_w, cursor, tlist, wlist, inv_slot);
    gateup_kernel<<<GU_NWG, 256, 0, stream>>>(xh, wg, wu, offsets, counts, tlist, hbuf);
    down_kernel<<<DN_NWG, 256, 0, stream>>>(hbuf, wd, offsets, counts, tlist, wlist, ybuf);
    reduce_kernel<<<T_TOK, 256, 0, stream>>>(ybuf, inv_slot, out);
}